// Round 9
// baseline (144.952 us; speedup 1.0000x reference)
//
#include <hip/hip_runtime.h>
#include <math.h>

#define BATCH 64
#define KSL   32
#define DIM   256
#define NMASK 16384

// DPP move, compile-time ctrl. bound_ctrl=false + old=src: disabled source
// lanes yield own value (min-safe).
template<int CTRL>
__device__ __forceinline__ float dpp_mov_f32(float x) {
  int xi = __float_as_int(x);
  int r = __builtin_amdgcn_update_dpp(xi, xi, CTRL, 0xF, 0xF, false);
  return __int_as_float(r);
}

template<int CTRL>
__device__ __forceinline__ double dpp_mov_f64(double x) {
  union { double d; int i[2]; } a, r;
  a.d = x;
  r.i[0] = __builtin_amdgcn_update_dpp(a.i[0], a.i[0], CTRL, 0xF, 0xF, false);
  r.i[1] = __builtin_amdgcn_update_dpp(a.i[1], a.i[1], CTRL, 0xF, 0xF, false);
  return r.d;
}

__device__ __forceinline__ double readlane_f64(double x, int lane) {
  union { double d; unsigned long long u; } a; a.d = x;
  int lo = __builtin_amdgcn_readlane((int)(a.u & 0xFFFFFFFFull), lane);
  int hi = __builtin_amdgcn_readlane((int)(a.u >> 32), lane);
  union { unsigned long long u; double d; } r;
  r.u = ((unsigned long long)(unsigned)hi << 32) | (unsigned)lo;
  return r.d;
}

// Branchless select cc[idx] (idx wave-uniform) via 5-level cndmask tree.
// Inputs are COMPUTED loop state (not pure LDS loads) -> cannot be
// rematerialized from memory by the compiler (rounds 4-6 failure mode).
__device__ __forceinline__ float sel32f(const float (&cc)[KSL], int idx) {
  float l0[16], l1[8], l2[4], l3[2];
  bool b4 = (idx & 16) != 0;
  #pragma unroll
  for (int r = 0; r < 16; ++r) l0[r] = b4 ? cc[r + 16] : cc[r];
  bool b3 = (idx & 8) != 0;
  #pragma unroll
  for (int r = 0; r < 8; ++r) l1[r] = b3 ? l0[r + 8] : l0[r];
  bool b2 = (idx & 4) != 0;
  #pragma unroll
  for (int r = 0; r < 4; ++r) l2[r] = b2 ? l1[r + 4] : l1[r];
  bool b1 = (idx & 2) != 0;
  #pragma unroll
  for (int r = 0; r < 2; ++r) l3[r] = b1 ? l2[r + 2] : l2[r];
  return (idx & 1) ? l3[1] : l3[0];
}

// ---------------------------------------------------------------------------
// Fused kernel:
//   blocks [0,64)        : cost matrix + reference-exact greedy assignment.
//     Chain restructure: the next row needed is ALWAYS the owner row of the
//     selected column -> keep ccOwn[c] = cs[p[c]-1][col] per lane, installed
//     once per outer step (static-address prefetched row). On-chain row
//     access = register cndmask tree, NOT a 110-cy dependent ds_read.
//     Selection: fp32 DPP min tree (monotone rounding) + exact fp64 tie
//     resolve. Bit-exact vs numpy in all cases (proven rounds 2-8).
//   blocks [64, 64+2048) : mask partial sums (134 MB, full-device streaming)
// ---------------------------------------------------------------------------
__global__ __launch_bounds__(256, 1) void fused_kernel(
    const float* __restrict__ slots_t, const float* __restrict__ slots_t1,
    const float* __restrict__ masks,
    int* __restrict__ match, float* __restrict__ partial) {
  int tid = threadIdx.x;
  if (blockIdx.x < BATCH) {
    int b = blockIdx.x;
    __shared__ float as[KSL][64];
    __shared__ float bs[KSL][65];   // pad: conflict-free
    __shared__ float cs[KSL][KSL];  // solver reads rows: stride-1 -> ok
    const float* ab = slots_t  + (size_t)b * KSL * DIM;
    const float* bb = slots_t1 + (size_t)b * KSL * DIM;

    // ---- cost[i][j] = ||a_i - b_j|| (fp32) ----
    float acc[4] = {0.f, 0.f, 0.f, 0.f};
    for (int c = 0; c < DIM / 64; ++c) {
      __syncthreads();
      for (int e = tid; e < KSL * 64; e += 256) {
        int kk = e >> 6, dd = e & 63;
        as[kk][dd] = ab[kk * DIM + c * 64 + dd];
        bs[kk][dd] = bb[kk * DIM + c * 64 + dd];
      }
      __syncthreads();
      #pragma unroll
      for (int p4 = 0; p4 < 4; ++p4) {
        int id = p4 * 256 + tid;
        int i = id >> 5, j = id & 31;
        float s = acc[p4];
        #pragma unroll
        for (int dd = 0; dd < 64; ++dd) {
          float df = as[i][dd] - bs[j][dd];
          s = fmaf(df, df, s);
        }
        acc[p4] = s;
      }
    }
    __syncthreads();
    #pragma unroll
    for (int p4 = 0; p4 < 4; ++p4) {
      int id = p4 * 256 + tid;
      cs[id >> 5][id & 31] = sqrtf(acc[p4]);
    }
    __syncthreads();
    if (tid >= 32) return;   // 32 lanes solve; no barriers below

    // ---- greedy assignment, reference-exact (fp64 duals) ----
    // lane col: v[col+1], pcol = p[col+1], up = u[p[col+1]],
    //           ccOwn[c] = cs[p[c+1]-1][col] (valid only for owned c)
    const int col = tid;
    const double INF64 = __builtin_inf();
    double v = 0.0, up = 0.0;
    int pcol = 0;
    unsigned freemask = 0xFFFFFFFFu;   // uniform: bit c set <=> p[c+1]==0
    float ccOwn[KSL];
    #pragma unroll
    for (int r = 0; r < KSL; ++r) ccOwn[r] = 0.f;

    float  cRow = cs[0][col];     // row for outer i=1 (static prefetch)
    double cd   = (double)cRow;   // c - u[i], u[i]=0
    for (int i = 1; i <= KSL; ++i) {
      double u_i = 0.0;
      int used = 0;
      for (;;) {
        double key64 = cd - v;               // fl(fl(c-u0)-v): ref order
        float  key32 = (float)key64;         // monotone rounding
        float  masked32 = used ? __builtin_inff() : key32;
        float m = masked32;
        m = fminf(m, dpp_mov_f32<0xB1>(m));  // quad_perm [1,0,3,2]
        m = fminf(m, dpp_mov_f32<0x4E>(m));  // quad_perm [2,3,0,1]
        m = fminf(m, dpp_mov_f32<0x141>(m)); // row_half_mirror
        m = fminf(m, dpp_mov_f32<0x140>(m)); // row_mirror
        m = fminf(m, dpp_mov_f32<0x142>(m)); // row_bcast15 -> lane31 = min32
        float min32 = __int_as_float(
            __builtin_amdgcn_readlane(__float_as_int(m), 31));
        unsigned eq = (unsigned)__ballot(masked32 == min32);
        int j1c;
        double delta;
        if (__popc(eq) == 1) {
          // unique fp32 min -> it is THE fp64 argmin (monotone rounding)
          j1c = __ffs(eq) - 1;
          delta = readlane_f64(key64, j1c);
        } else {
          // fp32 tie: exact fp64 resolve among candidates (rare)
          bool cand = (masked32 == min32);
          double kk = cand ? key64 : INF64;
          double md = kk;
          md = fmin(md, dpp_mov_f64<0xB1>(md));
          md = fmin(md, dpp_mov_f64<0x4E>(md));
          md = fmin(md, dpp_mov_f64<0x141>(md));
          md = fmin(md, dpp_mov_f64<0x140>(md));
          md = fmin(md, dpp_mov_f64<0x142>(md));
          delta = readlane_f64(md, 31);
          unsigned eq2 = (unsigned)__ballot(kk == delta);
          j1c = __ffs(eq2) - 1;               // lowest index: numpy tie rule
        }
        j1c = __builtin_amdgcn_readfirstlane(j1c);
        bool isfree = (freemask >> j1c) & 1u;  // uniform scalar test
        // dual updates: u[p[j]] += delta, v[j] -= delta for used j; u[i] too
        // (uses OLD 'used' flag; lane j1c was unused -> its up unchanged)
        if (used) { up += delta; v -= delta; }
        u_i += delta;
        if (isfree) {                        // free column: p[j1]=i, done
          if (col == j1c) { pcol = i; up = u_i; }
          freemask &= ~(1u << j1c);
          #pragma unroll                     // install owner-row cost for j1
          for (int r = 0; r < KSL; ++r)
            ccOwn[r] = (r == j1c) ? cRow : ccOwn[r];
          break;
        }
        if (col == j1c) used = 1;            // used[j1] = True
        // next row = owner of column j1: register select, no ds_read
        float  cSel = sel32f(ccOwn, j1c);
        double u0n  = readlane_f64(up, j1c); // u[p[j1]] (unchanged this iter)
        cd = (double)cSel - u0n;
      }
      if (i < KSL) {
        cRow = cs[i][col];                   // static-address prefetch
        cd = (double)cRow;                   // u[i+1] = 0
      }
    }
    match[b * KSL + (pcol - 1)] = col;       // ans[p[j]-1] = j-1
  } else {
    // ---- mask partial sums: partial[b][chunk][k], coalesced float4 ----
    int idx = blockIdx.x - BATCH;
    int b = idx >> 5, chunk = idx & 31;
    const int ROWS = NMASK / 32;  // 512 rows of 32 floats per chunk
    const float4* m4 = (const float4*)(masks + (size_t)b * NMASK * KSL +
                                       (size_t)chunk * ROWS * KSL);
    int q = tid & 7;
    int r = tid >> 3;
    float4 a4 = make_float4(0.f, 0.f, 0.f, 0.f);
    for (int rr = r; rr < ROWS; rr += 32) {
      float4 t = m4[rr * 8 + q];
      a4.x += t.x; a4.y += t.y; a4.z += t.z; a4.w += t.w;
    }
    __shared__ float red[256][4];
    red[tid][0] = a4.x; red[tid][1] = a4.y;
    red[tid][2] = a4.z; red[tid][3] = a4.w;
    __syncthreads();
    if (tid < KSL) {
      int qq = tid >> 2, c = tid & 3;
      float s = 0.f;
      for (int g = 0; g < 32; ++g) s += red[g * 8 + qq][c];
      partial[(size_t)b * 1024 + chunk * 32 + tid] = s;
    }
  }
}

// ---------------------------------------------------------------------------
// Finale: per-batch epilogue + deterministic last-block global reduce.
// counter memset to 0 in-stream each call; last block (old==63) sums the
// 64 bloss values in fixed lane order -> bit-deterministic output.
// ---------------------------------------------------------------------------
__global__ __launch_bounds__(256) void finale_kernel(
    const float* __restrict__ st, const float* __restrict__ st1,
    const int* __restrict__ match, const float* __restrict__ partial,
    float* __restrict__ bloss, unsigned* __restrict__ counter,
    float* __restrict__ out) {
  int b = blockIdx.x, tid = threadIdx.x;
  __shared__ float util[KSL], ls[KSL], red[256];
  __shared__ int sh_last;
  if (tid < KSL) {
    float s = 0.f;
    for (int c = 0; c < 32; ++c) s += partial[(size_t)b * 1024 + c * 32 + tid];
    util[tid] = s;
  }
  int k = tid >> 3, l8 = tid & 7;
  int mk = match[b * KSL + k];
  const float* x = st  + ((size_t)b * KSL + k)  * DIM;
  const float* y = st1 + ((size_t)b * KSL + mk) * DIM;
  float acc = 0.f;
  for (int d = l8; d < DIM; d += 8) {
    float df = x[d] - y[d];
    acc = fmaf(df, df, acc);
  }
  red[tid] = acc;
  __syncthreads();
  if (l8 == 0) {
    float s = 0.f;
    #pragma unroll
    for (int t = 0; t < 8; ++t) s += red[tid + t];
    ls[k] = s;
  }
  __syncthreads();
  if (tid == 0) {
    float us = 0.f;
    for (int kk = 0; kk < KSL; ++kk) us += util[kk];
    float s = 0.f;
    for (int kk = 0; kk < KSL; ++kk) s += ls[kk] * (util[kk] / us);
    bloss[b] = s;
    __threadfence();                       // release bloss[b]
    unsigned old = atomicAdd(counter, 1u); // device-scope
    sh_last = (old == BATCH - 1) ? 1 : 0;
  }
  __syncthreads();
  if (sh_last && tid < 64) {
    __threadfence();                       // acquire
    float v = atomicAdd(&bloss[tid], 0.0f);  // device-scope read (x+0=x)
    #pragma unroll
    for (int off = 32; off > 0; off >>= 1) v += __shfl_down(v, off);
    if (tid == 0) out[0] = v / (float)(BATCH * KSL);
  }
}

extern "C" void kernel_launch(void* const* d_in, const int* in_sizes, int n_in,
                              void* d_out, int out_size, void* d_ws, size_t ws_size,
                              hipStream_t stream) {
  const float* slots_t  = (const float*)d_in[0];
  const float* slots_t1 = (const float*)d_in[1];
  const float* masks    = (const float*)d_in[2];

  // ws layout: match 8KB | partial 256KB | bloss 256B | counter 4B
  char* ws = (char*)d_ws;
  int*      match   = (int*)     (ws);
  float*    partial = (float*)   (ws + 8192);
  float*    bloss   = (float*)   (ws + 8192 + 262144);
  unsigned* counter = (unsigned*)(ws + 8192 + 262144 + 256);

  hipMemsetAsync(counter, 0, sizeof(unsigned), stream);
  fused_kernel<<<BATCH + BATCH * 32, 256, 0, stream>>>(slots_t, slots_t1, masks,
                                                       match, partial);
  finale_kernel<<<BATCH, 256, 0, stream>>>(slots_t, slots_t1, match, partial,
                                           bloss, counter, (float*)d_out);
}

// Round 10
// 64.434 us; speedup vs baseline: 2.2496x; 2.2496x over previous
//
#include <hip/hip_runtime.h>
#include <math.h>

#define BATCH 64
#define KSL   32
#define DIM   256
#define NMASK 16384

// DPP move of a double (both 32-bit halves), compile-time ctrl.
// bound_ctrl=false + old=src: invalid source lanes keep own value (min-safe).
template<int CTRL>
__device__ __forceinline__ double dpp_mov_f64(double x) {
  union { double d; int i[2]; } a, r;
  a.d = x;
  r.i[0] = __builtin_amdgcn_update_dpp(a.i[0], a.i[0], CTRL, 0xF, 0xF, false);
  r.i[1] = __builtin_amdgcn_update_dpp(a.i[1], a.i[1], CTRL, 0xF, 0xF, false);
  return r.d;
}

__device__ __forceinline__ double readlane_f64(double x, int lane) {
  union { double d; unsigned long long u; } a; a.d = x;
  int lo = __builtin_amdgcn_readlane((int)(a.u & 0xFFFFFFFFull), lane);
  int hi = __builtin_amdgcn_readlane((int)(a.u >> 32), lane);
  union { unsigned long long u; double d; } r;
  r.u = ((unsigned long long)(unsigned)hi << 32) | (unsigned)lo;
  return r.d;
}

// ---------------------------------------------------------------------------
// Fused kernel (round-3 proven best: 63.9 us total):
//   blocks [0,64)        : cost matrix in LDS + reference-exact greedy
//                          assignment (fp64 duals; the reference's minv/way
//                          are never written back -> plain greedy chain).
//   blocks [64, 64+2048) : mask partial sums (134 MB, full-device streaming)
// NOTE (rounds 4-9): register-resident cost column / cndmask-select variants
// are 2-3x SLOWER at every launch-bounds setting; prefetch/fp32-tree edits
// measured neutral-to-worse vs this structure. Keep the LDS-read solver.
// ---------------------------------------------------------------------------
__global__ __launch_bounds__(256) void fused_kernel(
    const float* __restrict__ slots_t, const float* __restrict__ slots_t1,
    const float* __restrict__ masks,
    int* __restrict__ match, float* __restrict__ partial) {
  int tid = threadIdx.x;
  if (blockIdx.x < BATCH) {
    int b = blockIdx.x;
    __shared__ float as[KSL][64];
    __shared__ float bs[KSL][65];   // pad: conflict-free
    __shared__ float cs[KSL][KSL];
    const float* ab = slots_t  + (size_t)b * KSL * DIM;
    const float* bb = slots_t1 + (size_t)b * KSL * DIM;

    // ---- cost[i][j] = ||a_i - b_j|| (fp32) ----
    float acc[4] = {0.f, 0.f, 0.f, 0.f};
    for (int c = 0; c < DIM / 64; ++c) {
      __syncthreads();
      for (int e = tid; e < KSL * 64; e += 256) {
        int kk = e >> 6, dd = e & 63;
        as[kk][dd] = ab[kk * DIM + c * 64 + dd];
        bs[kk][dd] = bb[kk * DIM + c * 64 + dd];
      }
      __syncthreads();
      #pragma unroll
      for (int p4 = 0; p4 < 4; ++p4) {
        int id = p4 * 256 + tid;
        int i = id >> 5, j = id & 31;
        float s = acc[p4];
        #pragma unroll
        for (int dd = 0; dd < 64; ++dd) {
          float df = as[i][dd] - bs[j][dd];
          s = fmaf(df, df, s);
        }
        acc[p4] = s;
      }
    }
    __syncthreads();
    #pragma unroll
    for (int p4 = 0; p4 < 4; ++p4) {
      int id = p4 * 256 + tid;
      cs[id >> 5][id & 31] = sqrtf(acc[p4]);
    }
    __syncthreads();
    if (tid >= 32) return;   // 32 lanes solve; no barriers below

    // ---- reference-exact greedy (fp64 duals, fp32 cost upcast) ----
    // lane col holds: v[col+1], p[col+1] (pcol), u[p[col+1]] (up)
    const int col = tid;
    double v = 0.0, up = 0.0;
    int pcol = 0;
    unsigned freemask = 0xFFFFFFFFu;   // uniform: bit j set <=> p[j+1]==0
    for (int i = 1; i <= KSL; ++i) {
      double u_i = 0.0;
      int used = 0;
      int i0 = i;          // p[0] = i
      double u0 = 0.0;     // u[i] = 0 (row i unassigned so far)
      for (;;) {
        double cur = (double)cs[i0 - 1][col] - u0 - v;
        double masked = used ? __builtin_inf() : cur;
        // 32-lane fp64 min via DPP: quad xor1, xor2, half-mirror, mirror,
        // bcast15 (lane 31 ends with min of all 32 lanes). Exact selection.
        double m = masked;
        m = fmin(m, dpp_mov_f64<0xB1>(m));    // quad_perm [1,0,3,2]
        m = fmin(m, dpp_mov_f64<0x4E>(m));    // quad_perm [2,3,0,1]
        m = fmin(m, dpp_mov_f64<0x141>(m));   // row_half_mirror
        m = fmin(m, dpp_mov_f64<0x140>(m));   // row_mirror
        m = fmin(m, dpp_mov_f64<0x142>(m));   // row_bcast15
        double delta = readlane_f64(m, 31);   // uniform min value
        // j1 = lowest col attaining the min (numpy argmin tie-break)
        unsigned eq = (unsigned)__ballot(masked == delta);
        int j1c = __builtin_amdgcn_readfirstlane(__ffs(eq) - 1);
        // prefetch next hop BEFORE dual update (lane j1c's up/pcol are
        // unchanged this iteration: j1c was unused during the update)
        double u0n = readlane_f64(up, j1c);
        int    i0n = __builtin_amdgcn_readlane(pcol, j1c);
        // dual updates: u[p[j]] += delta, v[j] -= delta for used j; u[i] too
        if (used) { up += delta; v -= delta; }
        u_i += delta;
        if (freemask & (1u << j1c)) {        // free column -> assign p[j1]=i
          if (col == j1c) { pcol = i; up = u_i; }
          freemask &= ~(1u << j1c);
          break;
        }
        if (col == j1c) used = 1;            // used[j1] = True
        u0 = u0n;
        i0 = i0n;
      }
    }
    match[b * KSL + (pcol - 1)] = col;       // ans[p[j]-1] = j-1
  } else {
    // ---- mask partial sums: partial[b][chunk][k], coalesced float4 ----
    int idx = blockIdx.x - BATCH;
    int b = idx >> 5, chunk = idx & 31;
    const int ROWS = NMASK / 32;  // 512 rows of 32 floats per chunk
    const float4* m4 = (const float4*)(masks + (size_t)b * NMASK * KSL +
                                       (size_t)chunk * ROWS * KSL);
    int q = tid & 7;
    int r = tid >> 3;
    float4 a4 = make_float4(0.f, 0.f, 0.f, 0.f);
    for (int rr = r; rr < ROWS; rr += 32) {
      float4 t = m4[rr * 8 + q];
      a4.x += t.x; a4.y += t.y; a4.z += t.z; a4.w += t.w;
    }
    __shared__ float red[256][4];
    red[tid][0] = a4.x; red[tid][1] = a4.y;
    red[tid][2] = a4.z; red[tid][3] = a4.w;
    __syncthreads();
    if (tid < KSL) {
      int qq = tid >> 2, c = tid & 3;
      float s = 0.f;
      for (int g = 0; g < 32; ++g) s += red[g * 8 + qq][c];
      partial[(size_t)b * 1024 + chunk * 32 + tid] = s;
    }
  }
}

// ---------------------------------------------------------------------------
// Epilogue: reduce util partials, matched L2^2 per slot, weight, per-batch sum
// ---------------------------------------------------------------------------
__global__ __launch_bounds__(256) void final_kernel(
    const float* __restrict__ st, const float* __restrict__ st1,
    const int* __restrict__ match, const float* __restrict__ partial,
    float* __restrict__ bloss) {
  int b = blockIdx.x, tid = threadIdx.x;
  __shared__ float util[KSL], ls[KSL], red[256];
  if (tid < KSL) {
    float s = 0.f;
    for (int c = 0; c < 32; ++c) s += partial[(size_t)b * 1024 + c * 32 + tid];
    util[tid] = s;
  }
  int k = tid >> 3, l8 = tid & 7;
  int mk = match[b * KSL + k];
  const float* x = st  + ((size_t)b * KSL + k)  * DIM;
  const float* y = st1 + ((size_t)b * KSL + mk) * DIM;
  float acc = 0.f;
  for (int d = l8; d < DIM; d += 8) {
    float df = x[d] - y[d];
    acc = fmaf(df, df, acc);
  }
  red[tid] = acc;
  __syncthreads();
  if (l8 == 0) {
    float s = 0.f;
    #pragma unroll
    for (int t = 0; t < 8; ++t) s += red[tid + t];
    ls[k] = s;
  }
  __syncthreads();
  if (tid == 0) {
    float us = 0.f;
    for (int kk = 0; kk < KSL; ++kk) us += util[kk];
    float s = 0.f;
    for (int kk = 0; kk < KSL; ++kk) s += ls[kk] * (util[kk] / us);
    bloss[b] = s;
  }
}

__global__ void reduce_kernel(const float* __restrict__ bloss,
                              float* __restrict__ out) {
  float v = bloss[threadIdx.x];
  #pragma unroll
  for (int off = 32; off > 0; off >>= 1) v += __shfl_down(v, off);
  if (threadIdx.x == 0) out[0] = v / (float)(BATCH * KSL);
}

extern "C" void kernel_launch(void* const* d_in, const int* in_sizes, int n_in,
                              void* d_out, int out_size, void* d_ws, size_t ws_size,
                              hipStream_t stream) {
  const float* slots_t  = (const float*)d_in[0];
  const float* slots_t1 = (const float*)d_in[1];
  const float* masks    = (const float*)d_in[2];

  // workspace layout: match 8KB | partial 256KB | bloss 256B
  char* ws = (char*)d_ws;
  int*   match   = (int*)  (ws);
  float* partial = (float*)(ws + 2048 * 4);
  float* bloss   = (float*)(ws + 2048 * 4 + 65536 * 4);

  fused_kernel<<<BATCH + BATCH * 32, 256, 0, stream>>>(slots_t, slots_t1, masks,
                                                       match, partial);
  final_kernel<<<BATCH, 256, 0, stream>>>(slots_t, slots_t1, match, partial, bloss);
  reduce_kernel<<<1, 64, 0, stream>>>(bloss, (float*)d_out);
}